// Round 24
// baseline (157.738 us; speedup 1.0000x reference)
//
#include <hip/hip_runtime.h>
#include <hip/hip_bf16.h>

typedef __hip_bfloat16 bf16;
typedef __attribute__((ext_vector_type(8))) short bf16x8;
typedef __attribute__((ext_vector_type(4))) float f32x4;

#define MFMA_BF16(a, b, c) __builtin_amdgcn_mfma_f32_16x16x32_bf16((a), (b), (c), 0, 0, 0)

#define B_   2
#define S_   2048
#define HID_ 2048
#define H_   16
#define HKV_ 4
#define D_   128

#define GLOAD_LDS(gptr, lptr) \
  __builtin_amdgcn_global_load_lds((const __attribute__((address_space(1))) void*)(gptr), \
                                   (__attribute__((address_space(3))) void*)(lptr), 16, 0, 0)

template <int N>
__device__ __forceinline__ void vmw() {
  if constexpr (N == 0)      asm volatile("s_waitcnt vmcnt(0)" ::: "memory");
  else if constexpr (N == 4) asm volatile("s_waitcnt vmcnt(4)" ::: "memory");
  else if constexpr (N == 5) asm volatile("s_waitcnt vmcnt(5)" ::: "memory");
  else                       asm volatile("s_waitcnt vmcnt(6)" ::: "memory");
}

__device__ __forceinline__ void blk_barrier() {
  __builtin_amdgcn_sched_barrier(0);
  __builtin_amdgcn_s_barrier();
  __builtin_amdgcn_sched_barrier(0);
}

// ---------------------------------------------------------------- fp32 -> bf16 (all tensors) + seq_start
__global__ void cvt_all(const float* __restrict__ hidden, const float* __restrict__ Wq,
                        const float* __restrict__ Wk, const float* __restrict__ Wv,
                        const float* __restrict__ Wo, const int* __restrict__ seq,
                        bf16* __restrict__ Xb, bf16* __restrict__ Wqkv, bf16* __restrict__ Wob,
                        int* __restrict__ sstart) {
  if (blockIdx.x >= 2048) {
    int t = (blockIdx.x - 2048) * 256 + threadIdx.x;  // 0..8191
    int b = t >> 11, s = t & (S_ - 1);
    const int* sb = seq + b * S_;
    int sid = sb[s];
    int lo = 0, hi = s;
    while (lo < hi) {
      int mid = (lo + hi) >> 1;
      if (sb[mid] < sid) lo = mid + 1; else hi = mid;
    }
    sstart[t] = lo;
    return;
  }
  const long long total = 4718592;  // float4 items
  for (long long i4 = (long long)blockIdx.x * 256 + threadIdx.x; i4 < total; i4 += 2048LL * 256) {
    const float* src; bf16* dst; long long off;
    if (i4 < 2097152)      { src = hidden; dst = Xb;             off = i4; }
    else if (i4 < 3145728) { src = Wq;     dst = Wqkv;           off = i4 - 2097152; }
    else if (i4 < 3407872) { src = Wk;     dst = Wqkv + 4194304; off = i4 - 3145728; }
    else if (i4 < 3670016) { src = Wv;     dst = Wqkv + 5242880; off = i4 - 3407872; }
    else                   { src = Wo;     dst = Wob;            off = i4 - 3670016; }
    float4 v = *reinterpret_cast<const float4*>(src + off * 4);
    alignas(8) bf16 t[4];
    t[0] = __float2bfloat16(v.x);
    t[1] = __float2bfloat16(v.y);
    t[2] = __float2bfloat16(v.z);
    t[3] = __float2bfloat16(v.w);
    *reinterpret_cast<short4*>(dst + off * 4) = *reinterpret_cast<const short4*>(t);
  }
}

// ---------------------------------------------------------------- 4-phase GEMM, 4M x 2N wave decomposition
// C[M][N] = A[M][K]*B[N][K]^T.  BK=64; A in two k-halves [2][2][BM*32]; B flat [BN][64] per dbuf.
// 8 waves as 4M x 2N (was 2M x 4N): A-frag duplication 4 -> 2, per-tile LDS reads
// 176 -> 160 KB (QKV) / 160 -> 128 KB (O-proj) — LDS-read pipe is the binding pipe
// (needs ~2070 cy/tile vs MFMA ~930 at the old decomposition).
// Per-wave tile (BM/4) x (BN/2) = MR x NR frags; MH = MR/2 per phase.
// Phase = {ds_read frags | stage | MFMA | barrier}; one counted vmcnt (LB+2) per tile at P4.
// Swizzles: A 16B-slot' = slot ^ ((row>>1)&3); B slot' = slot ^ (row&7). Same algebraic
// read form (16 consecutive rows x XOR slot) -> stays conflict-free.
// launch_bounds min-waves MUST stay 2 (R14 spill lesson). 2-barrier merge regressed (R21).
template <int BM, int BN, int OUT_BF16>
__global__ __launch_bounds__(512, 2) void gemm8p(const bf16* __restrict__ A,
                                                 const bf16* __restrict__ Bw,
                                                 void* __restrict__ Cout,
                                                 int M, int N, int K) {
  constexpr int MR = BM / 64;       // per-wave m-frags (4)
  constexpr int MH = MR / 2;        // frags per phase-half (2)
  constexpr int NR = BN / 32;       // per-wave n-frags (6 for 192, 4 for 128)
  constexpr int LB = BN / 64;       // B stage passes (3 or 2)
  constexpr int LA = BM / 128;      // A stage passes per k-half (2)
  constexpr int QD = LB + 2;        // steady-state vmcnt

  __shared__ bf16 As[2][2][BM * 32];   // [dbuf][khalf]
  __shared__ bf16 Bs[2][BN * 64];      // [dbuf], flat full-BK tile

  const int tid  = threadIdx.x;
  const int lane = tid & 63;
  const int w    = tid >> 6;
  const int wrow = w >> 1;          // 0..3
  const int wcol = w & 1;           // 0..1
  const int ln15 = lane & 15, g = lane >> 4;

  const int nwg = gridDim.x;
  int bid = blockIdx.x;
  bid = (bid & 7) * (nwg >> 3) + (bid >> 3);
  const int nbn = N / BN;
  const int m0 = (bid / nbn) * BM;
  const int n0 = (bid % nbn) * BN;

  f32x4 acc[MR][NR] = {};

  auto stageA = [&](int db, int kh, int t) {
    int kc = t * 64 + kh * 32;
#pragma unroll
    for (int r = 0; r < LA; r++) {
      int sIdx = r * 512 + tid;
      int row = sIdx >> 2;
      int ss = (sIdx & 3) ^ ((row >> 1) & 3);
      GLOAD_LDS(A + (size_t)(m0 + row) * K + kc + ss * 8, &As[db][kh][(r * 512 + w * 64) * 8]);
    }
  };
  auto stageB = [&](int db, int t) {
#pragma unroll
    for (int r = 0; r < LB; r++) {
      int sIdx = r * 512 + tid;
      int row = sIdx >> 3;
      int cs = (sIdx & 7) ^ (row & 7);
      GLOAD_LDS(Bw + (size_t)(n0 + row) * K + t * 64 + cs * 8, &Bs[db][(size_t)(r * 512 + w * 64) * 8]);
    }
  };

  bf16x8 af[MH], bfr[NR];
  auto rdA = [&](int db, int kh, int mh) {
#pragma unroll
    for (int m = 0; m < MH; m++) {
      int row = wrow * (BM / 4) + (mh * MH + m) * 16 + ln15;
      af[m] = *reinterpret_cast<const bf16x8*>(&As[db][kh][row * 32 + ((g ^ ((row >> 1) & 3)) << 3)]);
    }
  };
  auto rdB = [&](int db, int kh) {
#pragma unroll
    for (int n = 0; n < NR; n++) {
      int row = wcol * (BN / 2) + n * 16 + ln15;
      int sl = ((kh << 2) + g) ^ (row & 7);
      bfr[n] = *reinterpret_cast<const bf16x8*>(&Bs[db][row * 64 + sl * 8]);
    }
  };
  auto MF = [&](int mh) {
    __builtin_amdgcn_s_setprio(1);
#pragma unroll
    for (int m = 0; m < MH; m++)
#pragma unroll
      for (int n = 0; n < NR; n++)
        acc[mh * MH + m][n] = MFMA_BF16(af[m], bfr[n], acc[mh * MH + m][n]);
    __builtin_amdgcn_s_setprio(0);
  };

  const int NT = K >> 6;  // 32

  stageA(0, 0, 0);
  stageA(0, 1, 0);
  stageB(0, 0);
  stageA(1, 0, 1);
  stageB(1, 1);
  vmw<QD>();
  blk_barrier();

  for (int T = 0; T < NT; ++T) {
    const int db = T & 1, dn = db ^ 1;

    // P1: kh0, mh0 | stage A-kh1(T+1)
    rdA(db, 0, 0); rdB(db, 0);
    if (T + 1 < NT) stageA(dn, 1, T + 1);
    MF(0); blk_barrier();

    // P2: kh0, mh1
    rdA(db, 0, 1);
    MF(1); blk_barrier();

    // P3: kh1, mh0 | stage A-kh0(T+2)
    rdA(db, 1, 0); rdB(db, 1);
    if (T + 2 < NT) stageA(db, 0, T + 2);
    MF(0); blk_barrier();

    // P4: kh1, mh1 | stage B(T+2) | vmcnt | barrier
    rdA(db, 1, 1);
    if (T + 2 < NT) stageB(db, T + 2);
    MF(1);
    if (T + 1 < NT) {
      if (T == NT - 2) vmw<0>(); else vmw<QD>();
    }
    blk_barrier();
  }

#pragma unroll
  for (int m = 0; m < MR; m++)
#pragma unroll
    for (int n = 0; n < NR; n++)
#pragma unroll
      for (int r = 0; r < 4; r++) {
        int row = m0 + wrow * (BM / 4) + m * 16 + g * 4 + r;
        int col = n0 + wcol * (BN / 2) + n * 16 + ln15;
        if constexpr (OUT_BF16) {
          ((bf16*)Cout)[(size_t)row * N + col] = __float2bfloat16(acc[m][n][r]);
        } else {
          ((float*)Cout)[(size_t)row * N + col] = acc[m][n][r];
        }
      }
}

// ---------------------------------------------------------------- clip + RoPE (Q,K) + V transpose, one launch
__global__ __launch_bounds__(256) void qkv_post(const bf16* __restrict__ QKV,
                                                const int* __restrict__ wpos,
                                                bf16* __restrict__ Qs,   // [B][H][S][D]
                                                bf16* __restrict__ Ks,   // [B][HKV][S][D]
                                                bf16* __restrict__ Vt) { // [B][HKV][D][S]
  __shared__ bf16 Tl[64][132];
  const int t = threadIdx.x;

  if (blockIdx.x >= 4096) {
    const int blk = blockIdx.x - 4096;    // (b*HKV + kvh)*32 + st
    const int st = blk & 31, kvh = (blk >> 5) & 3, b = blk >> 7;
    const int s0 = st * 64;
#pragma unroll
    for (int p = 0; p < 8; p++) {
      int r = p * 8 + (t >> 5);
      int c = (t & 31) * 4;
      short4 v = *reinterpret_cast<const short4*>(QKV + (size_t)(b * S_ + s0 + r) * 3072 + 2560 + kvh * 128 + c);
      alignas(8) bf16 e[4];
      *reinterpret_cast<short4*>(e) = v;
#pragma unroll
      for (int k = 0; k < 4; k++) {
        float x = __bfloat162float(e[k]);
        x = fminf(fmaxf(x, -8.f), 8.f);
        Tl[r][c + k] = __float2bfloat16(x);
      }
    }
    __syncthreads();
    if (t < 128) {
      const int d = t;
      bf16* dst = Vt + ((size_t)(b * HKV_ + kvh) * D_ + d) * S_ + s0;
#pragma unroll
      for (int j = 0; j < 64; j += 8) {
        alignas(16) bf16 v[8];
#pragma unroll
        for (int k = 0; k < 8; k++) v[k] = Tl[j + k][d];
        *reinterpret_cast<short4*>(dst + j)     = *reinterpret_cast<const short4*>(&v[0]);
        *reinterpret_cast<short4*>(dst + j + 4) = *reinterpret_cast<const short4*>(&v[4]);
      }
    }
    return;
  }

  const int row = blockIdx.x;  // b*S + s
  const int b = row >> 11, s = row & (S_ - 1);
  const bf16* R = QKV + (size_t)row * 3072;
  const float pos = (float)wpos[row];
  const float kln = 0.14391156831212787f;   // ln(10000)/64
  const float qscale = 0.08838834764831845f; // 1/sqrt(128)

  const int i = t & 63;          // rotary index, fixed per thread
  const int hq = t >> 6;         // base head offset (0..3)
  float sn, cs;
  {
    float ang = pos * expf(-(float)i * kln);
    sincosf(ang, &sn, &cs);
  }

#pragma unroll
  for (int it = 0; it < 4; it++) {
    int h = hq + it * 4;
    float x1 = __bfloat162float(R[h * 128 + i]);
    float x2 = __bfloat162float(R[h * 128 + 64 + i]);
    x1 = fminf(fmaxf(x1, -8.f), 8.f);
    x2 = fminf(fmaxf(x2, -8.f), 8.f);
    float y1 = (x1 * cs - x2 * sn) * qscale;
    float y2 = (x2 * cs + x1 * sn) * qscale;
    size_t qb = ((size_t)(b * H_ + h) * S_ + s) * D_;
    Qs[qb + i]      = __float2bfloat16(y1);
    Qs[qb + 64 + i] = __float2bfloat16(y2);
  }
  {
    int kh = hq;
    float x1 = __bfloat162float(R[2048 + kh * 128 + i]);
    float x2 = __bfloat162float(R[2048 + kh * 128 + 64 + i]);
    x1 = fminf(fmaxf(x1, -8.f), 8.f);
    x2 = fminf(fmaxf(x2, -8.f), 8.f);
    float y1 = x1 * cs - x2 * sn;
    float y2 = x2 * cs + x1 * sn;
    size_t kb = ((size_t)(b * HKV_ + kh) * S_ + s) * D_;
    Ks[kb + i]      = __float2bfloat16(y1);
    Ks[kb + 64 + i] = __float2bfloat16(y2);
  }
}

// ---------------------------------------------------------------- flash attention, QBLK=32/wave, LDS-staged
__global__ __launch_bounds__(256) void attn_fwd(const bf16* __restrict__ Qs,
                                                const bf16* __restrict__ Ks,
                                                const bf16* __restrict__ Vt,
                                                const int* __restrict__ sstart,
                                                bf16* __restrict__ att) {  // [B][S][H*D]
  __shared__ bf16 Kl[2][32 * 128];
  __shared__ bf16 Vl[2][128 * 32];
  __shared__ bf16 Plds[4][2][16 * 40];   // padded rows (80 B stride, conflict-free)

  const int tid = threadIdx.x;
  const int lane = tid & 63, w = tid >> 6;
  const int ln15 = lane & 15, g = lane >> 4;

  const int wg = ((blockIdx.x & 7) << 6) | (blockIdx.x >> 3);
  const int qt  = wg & 63;
  const int kvh = (wg >> 6) & 3;
  const int b   = wg >> 8;
  const int h   = kvh * 4 + w;
  const int q0  = qt * 32;
  const int qa  = q0 + ln15;
  const int qb  = q0 + 16 + ln15;

  const bf16* Qbase = Qs + (size_t)(b * H_ + h) * S_ * D_;
  bf16x8 qfa[4], qfb[4];
#pragma unroll
  for (int c = 0; c < 4; c++) {
    qfa[c] = *reinterpret_cast<const bf16x8*>(Qbase + (size_t)qa * D_ + c * 32 + g * 8);
    qfb[c] = *reinterpret_cast<const bf16x8*>(Qbase + (size_t)qb * D_ + c * 32 + g * 8);
  }

  const int sQa = sstart[b * S_ + qa];
  const int sQb = sstart[b * S_ + qb];
  const int kstart = __builtin_amdgcn_readfirstlane(__shfl(sQa, 0));
  const int kend = q0 + 31;

  const bf16* Kb = Ks + (size_t)(b * HKV_ + kvh) * S_ * D_;
  const bf16* Vb = Vt + (size_t)(b * HKV_ + kvh) * D_ * S_;

  auto stage = [&](int buf, int kb) {
#pragma unroll
    for (int p = 0; p < 2; p++) {
      int slot = p * 256 + tid;
      int row = slot >> 4;
      int cs = (slot & 15) ^ (row & 15);
      int gr = min(kb + row, S_ - 1);
      GLOAD_LDS(Kb + (size_t)gr * D_ + cs * 8, &Kl[buf][(p * 256 + w * 64) * 8]);
    }
#pragma unroll
    for (int p = 0; p < 2; p++) {
      int slot = p * 256 + tid;
      int d = slot >> 2, c = slot & 3;
      int cs = c ^ (d & 3);
      int gcol = min(kb + cs * 8, S_ - 8);
      GLOAD_LDS(Vb + (size_t)d * S_ + gcol, &Vl[buf][(p * 256 + w * 64) * 8]);
    }
  };

  float ma = -1e30f, la = 0.f, mb = -1e30f, lb = 0.f;
  f32x4 oa[8] = {}, ob[8] = {};

  auto softmax = [&](const f32x4& s0, const f32x4& s1, int qi, int sQ, int kb,
                     float& m, float& lsum, f32x4 (&o)[8], bf16* pdst) {
    float sc[8];
    float tmax = -1e30f;
#pragma unroll
    for (int r = 0; r < 4; r++) {
      int k0i = kb + g * 4 + r;
      int k1i = k0i + 16;
      float x0 = (k0i >= sQ && k0i <= qi) ? s0[r] : -1e30f;
      float x1 = (k1i >= sQ && k1i <= qi) ? s1[r] : -1e30f;
      sc[r] = x0;
      sc[4 + r] = x1;
      tmax = fmaxf(tmax, fmaxf(x0, x1));
    }
    tmax = fmaxf(tmax, __shfl_xor(tmax, 16));
    tmax = fmaxf(tmax, __shfl_xor(tmax, 32));
    float mn  = fmaxf(m, tmax);
    float fac = __expf(m - mn);
    float ps = 0.f;
    alignas(16) bf16 pb[8];
#pragma unroll
    for (int i2 = 0; i2 < 8; i2++) {
      float p = (sc[i2] < -1e29f) ? 0.f : __expf(sc[i2] - mn);
      ps += p;
      pb[i2] = __float2bfloat16(p);
    }
    ps += __shfl_xor(ps, 16);
    ps += __shfl_xor(ps, 32);
    lsum = lsum * fac + ps;
    m = mn;
#pragma unroll
    for (int t2 = 0; t2 < 8; t2++) o[t2] *= fac;
    *reinterpret_cast<short4*>(pdst + ln15 * 40 + g * 4)      = *reinterpret_cast<const short4*>(&pb[0]);
    *reinterpret_cast<short4*>(pdst + ln15 * 40 + 16 + g * 4) = *reinterpret_cast<const short4*>(&pb[4]);
  };

  stage(0, kstart);
  int buf = 0;
  for (int kb = kstart; kb <= kend; kb += 32) {
    __syncthreads();
    if (kb + 32 <= kend) stage(buf ^ 1, kb + 32);

    bf16x8 kf0[4], kf1[4];
#pragma unroll
    for (int c = 0; c < 4; c++) {
      kf0[c] = *reinterpret_cast<const bf16x8*>(&Kl[buf][ln15 * 128 + (((c * 4 + g) ^ ln15) << 3)]);
      kf1[c] = *reinterpret_cast<const bf16x8*>(&Kl[buf][(16 + ln15) * 128 + (((c * 4 + g) ^ ln15) << 3)]);
    }
    f32x4 sa0 = {0.f, 0.f, 0.f, 0.f}, sa1 = sa0, sb0 = sa0, sb1 = sa0;
#pragma unroll
    for (int c = 0; c < 4; c++) {
      sa0 = MFMA_BF16(kf0[c], qfa[c], sa0);
      sa1 = MFMA_BF16(kf1[c], qfa[c], sa1);
      sb0 = MFMA_BF16(kf0[c], qfb[c], sb0);
      sb1 = MFMA_BF16(kf1[c], qfb[c], sb1);
    }

    softmax(sa0, sa1, qa, sQa, kb, ma, la, oa, &Plds[w][0][0]);
    softmax(sb0, sb1, qb, sQb, kb, mb, lb, ob, &Plds[w][1][0]);
    __builtin_amdgcn_wave_barrier();
    bf16x8 pfa = *reinterpret_cast<const bf16x8*>(&Plds[w][0][ln15 * 40 + g * 8]);
    bf16x8 pfb = *reinterpret_cast<const bf16x8*>(&Plds[w][1][ln15 * 40 + g * 8]);

#pragma unroll
    for (int t2 = 0; t2 < 8; t2++) {
      int d = t2 * 16 + ln15;
      bf16x8 vf = *reinterpret_cast<const bf16x8*>(&Vl[buf][d * 32 + ((g ^ (ln15 & 3)) << 3)]);
      oa[t2] = MFMA_BF16(vf, pfa, oa[t2]);
      ob[t2] = MFMA_BF16(vf, pfb, ob[t2]);
    }
    __builtin_amdgcn_wave_barrier();
    buf ^= 1;
  }

  float inva = 1.f / la;
  float invb = 1.f / lb;
#pragma unroll
  for (int t2 = 0; t2 < 8; t2++)
#pragma unroll
    for (int r = 0; r < 4; r++) {
      int d = t2 * 16 + g * 4 + r;
      att[((size_t)(b * S_ + qa)) * (H_ * D_) + h * D_ + d] = __float2bfloat16(oa[t2][r] * inva);
      att[((size_t)(b * S_ + qb)) * (H_ * D_) + h * D_ + d] = __float2bfloat16(ob[t2][r] * invb);
    }
}

// ---------------------------------------------------------------- launcher
extern "C" void kernel_launch(void* const* d_in, const int* in_sizes, int n_in,
                              void* d_out, int out_size, void* d_ws, size_t ws_size,
                              hipStream_t stream) {
  const float* hidden = (const float*)d_in[0];
  const int* wpos = (const int*)d_in[1];
  const int* seq = (const int*)d_in[3];
  const float* Wq = (const float*)d_in[4];
  const float* Wk = (const float*)d_in[5];
  const float* Wv = (const float*)d_in[6];
  const float* Wo = (const float*)d_in[7];

  char* ws = (char*)d_ws;
  bf16* Xb   = (bf16*)(ws);
  bf16* Wqkv = (bf16*)(ws + 16777216);
  bf16* Wob  = (bf16*)(ws + 29360128);
  bf16* QKVb = (bf16*)(ws + 37748736);
  bf16* Ksb  = (bf16*)(ws + 62914560);
  bf16* Vtb  = (bf16*)(ws + 67108864);
  int*  sst  = (int*)(ws + 71303168);
  bf16* Qsb  = Xb;
  bf16* attb = QKVb;

  cvt_all<<<dim3(2080), dim3(256), 0, stream>>>(hidden, Wq, Wk, Wv, Wo, seq, Xb, Wqkv, Wob, sst);

  // QKV projection: [4096,2048] x [3072,2048]^T -> bf16 [4096,3072]; grid 16x16=256
  gemm8p<256, 192, 1><<<dim3(256), dim3(512), 0, stream>>>(Xb, Wqkv, (void*)QKVb, 4096, 3072, 2048);

  qkv_post<<<dim3(4352), dim3(256), 0, stream>>>(QKVb, wpos, Qsb, Ksb, Vtb);

  attn_fwd<<<dim3(512), dim3(256), 0, stream>>>(Qsb, Ksb, Vtb, sst, attb);

  // O projection: [4096,2048] x [2048,2048]^T -> fp32 d_out; grid 16x16=256
  gemm8p<256, 128, 0><<<dim3(256), dim3(512), 0, stream>>>(attb, Wob, d_out, 4096, 2048, 2048);
}

// Round 25
// 157.729 us; speedup vs baseline: 1.0001x; 1.0001x over previous
//
#include <hip/hip_runtime.h>
#include <hip/hip_bf16.h>

typedef __hip_bfloat16 bf16;
typedef __attribute__((ext_vector_type(8))) short bf16x8;
typedef __attribute__((ext_vector_type(4))) float f32x4;

#define MFMA_BF16(a, b, c) __builtin_amdgcn_mfma_f32_16x16x32_bf16((a), (b), (c), 0, 0, 0)

#define B_   2
#define S_   2048
#define HID_ 2048
#define H_   16
#define HKV_ 4
#define D_   128

#define GLOAD_LDS(gptr, lptr) \
  __builtin_amdgcn_global_load_lds((const __attribute__((address_space(1))) void*)(gptr), \
                                   (__attribute__((address_space(3))) void*)(lptr), 16, 0, 0)

template <int N>
__device__ __forceinline__ void vmw() {
  if constexpr (N == 0)      asm volatile("s_waitcnt vmcnt(0)" ::: "memory");
  else if constexpr (N == 4) asm volatile("s_waitcnt vmcnt(4)" ::: "memory");
  else if constexpr (N == 5) asm volatile("s_waitcnt vmcnt(5)" ::: "memory");
  else                       asm volatile("s_waitcnt vmcnt(6)" ::: "memory");
}

__device__ __forceinline__ void blk_barrier() {
  __builtin_amdgcn_sched_barrier(0);
  __builtin_amdgcn_s_barrier();
  __builtin_amdgcn_sched_barrier(0);
}

// ---------------------------------------------------------------- fp32 -> bf16 (all tensors) + seq_start
// Grid-stride (2048 blocks x 256 thr, ~9 float4/thread). Blocks >= 2048 do seq_start.
__global__ void cvt_all(const float* __restrict__ hidden, const float* __restrict__ Wq,
                        const float* __restrict__ Wk, const float* __restrict__ Wv,
                        const float* __restrict__ Wo, const int* __restrict__ seq,
                        bf16* __restrict__ Xb, bf16* __restrict__ Wqkv, bf16* __restrict__ Wob,
                        int* __restrict__ sstart) {
  if (blockIdx.x >= 2048) {
    int t = (blockIdx.x - 2048) * 256 + threadIdx.x;  // 0..8191
    int b = t >> 11, s = t & (S_ - 1);
    const int* sb = seq + b * S_;
    int sid = sb[s];
    int lo = 0, hi = s;
    while (lo < hi) {
      int mid = (lo + hi) >> 1;
      if (sb[mid] < sid) lo = mid + 1; else hi = mid;
    }
    sstart[t] = lo;
    return;
  }
  const long long total = 4718592;  // float4 items
  for (long long i4 = (long long)blockIdx.x * 256 + threadIdx.x; i4 < total; i4 += 2048LL * 256) {
    const float* src; bf16* dst; long long off;
    if (i4 < 2097152)      { src = hidden; dst = Xb;             off = i4; }
    else if (i4 < 3145728) { src = Wq;     dst = Wqkv;           off = i4 - 2097152; }
    else if (i4 < 3407872) { src = Wk;     dst = Wqkv + 4194304; off = i4 - 3145728; }
    else if (i4 < 3670016) { src = Wv;     dst = Wqkv + 5242880; off = i4 - 3407872; }
    else                   { src = Wo;     dst = Wob;            off = i4 - 3670016; }
    float4 v = *reinterpret_cast<const float4*>(src + off * 4);
    alignas(8) bf16 t[4];
    t[0] = __float2bfloat16(v.x);
    t[1] = __float2bfloat16(v.y);
    t[2] = __float2bfloat16(v.z);
    t[3] = __float2bfloat16(v.w);
    *reinterpret_cast<short4*>(dst + off * 4) = *reinterpret_cast<const short4*>(t);
  }
}

// ---------------------------------------------------------------- 4-phase GEMM, single barrier/phase (locked best)
// C[M][N] = A[M][K]*B[N][K]^T.  BK=64; A in two k-halves [2][2][BM*32]; B flat [BN][64] per dbuf.
// 8 waves (2M x 4N), per-wave (BM/2) x (BN/4) = MR x NR 16x16 frags, MH=MR/2 per phase.
// Phase = {ds_read frags | stage | MFMA | barrier}; one counted vmcnt (NR+2) per tile at P4.
// Swizzles: A 16B-slot' = slot ^ ((row>>1)&3); B slot' = slot ^ (row&7). 0 conflicts measured.
// Ledger: coarse-counted (R8), frag read-ahead (R12), 80KB diet (R13/15), (512,4) spill (R14),
// 32x32 MFMA (R9), 2-barrier merge (R21), 4Mx2N decomp (R24) — all neutral or worse.
// This 4-phase form at 2Mx4N is the measured best (~57.2 us, ~900 TF, MfmaUtil 35%).
template <int BM, int BN, int OUT_BF16>
__global__ __launch_bounds__(512, 2) void gemm8p(const bf16* __restrict__ A,
                                                 const bf16* __restrict__ Bw,
                                                 void* __restrict__ Cout,
                                                 int M, int N, int K) {
  constexpr int MR = BM / 32;       // 8
  constexpr int MH = MR / 2;        // frags per phase-half
  constexpr int NR = BN / 64;       // 3 (BN=192) or 2 (BN=128)
  constexpr int LA = BM / 128;      // 2
  constexpr int QD = NR + 2;        // steady-state vmcnt

  __shared__ bf16 As[2][2][BM * 32];   // [dbuf][khalf]
  __shared__ bf16 Bs[2][BN * 64];      // [dbuf], flat full-BK tile

  const int tid  = threadIdx.x;
  const int lane = tid & 63;
  const int w    = tid >> 6;
  const int wr   = w >> 2;          // 0..1
  const int wc   = w & 3;           // 0..3
  const int ln15 = lane & 15, g = lane >> 4;

  const int nwg = gridDim.x;
  int bid = blockIdx.x;
  bid = (bid & 7) * (nwg >> 3) + (bid >> 3);
  const int nbn = N / BN;
  const int m0 = (bid / nbn) * BM;
  const int n0 = (bid % nbn) * BN;

  f32x4 acc[MR][NR] = {};

  auto stageA = [&](int db, int kh, int t) {
    int kc = t * 64 + kh * 32;
#pragma unroll
    for (int r = 0; r < LA; r++) {
      int sIdx = r * 512 + tid;
      int row = sIdx >> 2;
      int ss = (sIdx & 3) ^ ((row >> 1) & 3);
      GLOAD_LDS(A + (size_t)(m0 + row) * K + kc + ss * 8, &As[db][kh][(r * 512 + w * 64) * 8]);
    }
  };
  auto stageB = [&](int db, int t) {
#pragma unroll
    for (int r = 0; r < NR; r++) {
      int sIdx = r * 512 + tid;
      int row = sIdx >> 3;
      int cs = (sIdx & 7) ^ (row & 7);
      GLOAD_LDS(Bw + (size_t)(n0 + row) * K + t * 64 + cs * 8, &Bs[db][(size_t)(r * 512 + w * 64) * 8]);
    }
  };

  bf16x8 af[MH], bfr[NR];
  auto rdA = [&](int db, int kh, int mh) {
#pragma unroll
    for (int m = 0; m < MH; m++) {
      int row = wr * (BM / 2) + (mh * MH + m) * 16 + ln15;
      af[m] = *reinterpret_cast<const bf16x8*>(&As[db][kh][row * 32 + ((g ^ ((row >> 1) & 3)) << 3)]);
    }
  };
  auto rdB = [&](int db, int kh) {
#pragma unroll
    for (int n = 0; n < NR; n++) {
      int row = wc * (BN / 4) + n * 16 + ln15;
      int sl = ((kh << 2) + g) ^ (row & 7);
      bfr[n] = *reinterpret_cast<const bf16x8*>(&Bs[db][row * 64 + sl * 8]);
    }
  };
  auto MF = [&](int mh) {
    __builtin_amdgcn_s_setprio(1);
#pragma unroll
    for (int m = 0; m < MH; m++)
#pragma unroll
      for (int n = 0; n < NR; n++)
        acc[mh * MH + m][n] = MFMA_BF16(af[m], bfr[n], acc[mh * MH + m][n]);
    __builtin_amdgcn_s_setprio(0);
  };

  const int NT = K >> 6;  // 32

  stageA(0, 0, 0);
  stageA(0, 1, 0);
  stageB(0, 0);
  stageA(1, 0, 1);
  stageB(1, 1);
  vmw<QD>();
  blk_barrier();

  for (int T = 0; T < NT; ++T) {
    const int db = T & 1, dn = db ^ 1;

    // P1: kh0, mh0 | stage A-kh1(T+1)
    rdA(db, 0, 0); rdB(db, 0);
    if (T + 1 < NT) stageA(dn, 1, T + 1);
    MF(0); blk_barrier();

    // P2: kh0, mh1
    rdA(db, 0, 1);
    MF(1); blk_barrier();

    // P3: kh1, mh0 | stage A-kh0(T+2)
    rdA(db, 1, 0); rdB(db, 1);
    if (T + 2 < NT) stageA(db, 0, T + 2);
    MF(0); blk_barrier();

    // P4: kh1, mh1 | stage B(T+2) | vmcnt | barrier
    rdA(db, 1, 1);
    if (T + 2 < NT) stageB(db, T + 2);
    MF(1);
    if (T + 1 < NT) {
      if (T == NT - 2) vmw<0>(); else vmw<QD>();
    }
    blk_barrier();
  }

#pragma unroll
  for (int m = 0; m < MR; m++)
#pragma unroll
    for (int n = 0; n < NR; n++)
#pragma unroll
      for (int r = 0; r < 4; r++) {
        int row = m0 + wr * (BM / 2) + m * 16 + g * 4 + r;
        int col = n0 + wc * (BN / 4) + n * 16 + ln15;
        if constexpr (OUT_BF16) {
          ((bf16*)Cout)[(size_t)row * N + col] = __float2bfloat16(acc[m][n][r]);
        } else {
          ((float*)Cout)[(size_t)row * N + col] = acc[m][n][r];
        }
      }
}

// ---------------------------------------------------------------- clip + RoPE (Q,K) + V transpose, one launch
__global__ __launch_bounds__(256) void qkv_post(const bf16* __restrict__ QKV,
                                                const int* __restrict__ wpos,
                                                bf16* __restrict__ Qs,   // [B][H][S][D]
                                                bf16* __restrict__ Ks,   // [B][HKV][S][D]
                                                bf16* __restrict__ Vt) { // [B][HKV][D][S]
  __shared__ bf16 Tl[64][132];
  const int t = threadIdx.x;

  if (blockIdx.x >= 4096) {
    const int blk = blockIdx.x - 4096;    // (b*HKV + kvh)*32 + st
    const int st = blk & 31, kvh = (blk >> 5) & 3, b = blk >> 7;
    const int s0 = st * 64;
#pragma unroll
    for (int p = 0; p < 8; p++) {
      int r = p * 8 + (t >> 5);
      int c = (t & 31) * 4;
      short4 v = *reinterpret_cast<const short4*>(QKV + (size_t)(b * S_ + s0 + r) * 3072 + 2560 + kvh * 128 + c);
      alignas(8) bf16 e[4];
      *reinterpret_cast<short4*>(e) = v;
#pragma unroll
      for (int k = 0; k < 4; k++) {
        float x = __bfloat162float(e[k]);
        x = fminf(fmaxf(x, -8.f), 8.f);
        Tl[r][c + k] = __float2bfloat16(x);
      }
    }
    __syncthreads();
    if (t < 128) {
      const int d = t;
      bf16* dst = Vt + ((size_t)(b * HKV_ + kvh) * D_ + d) * S_ + s0;
#pragma unroll
      for (int j = 0; j < 64; j += 8) {
        alignas(16) bf16 v[8];
#pragma unroll
        for (int k = 0; k < 8; k++) v[k] = Tl[j + k][d];
        *reinterpret_cast<short4*>(dst + j)     = *reinterpret_cast<const short4*>(&v[0]);
        *reinterpret_cast<short4*>(dst + j + 4) = *reinterpret_cast<const short4*>(&v[4]);
      }
    }
    return;
  }

  const int row = blockIdx.x;  // b*S + s
  const int b = row >> 11, s = row & (S_ - 1);
  const bf16* R = QKV + (size_t)row * 3072;
  const float pos = (float)wpos[row];
  const float kln = 0.14391156831212787f;   // ln(10000)/64
  const float qscale = 0.08838834764831845f; // 1/sqrt(128)

  const int i = t & 63;          // rotary index, fixed per thread
  const int hq = t >> 6;         // base head offset (0..3)
  float sn, cs;
  {
    float ang = pos * expf(-(float)i * kln);
    sincosf(ang, &sn, &cs);
  }

#pragma unroll
  for (int it = 0; it < 4; it++) {
    int h = hq + it * 4;
    float x1 = __bfloat162float(R[h * 128 + i]);
    float x2 = __bfloat162float(R[h * 128 + 64 + i]);
    x1 = fminf(fmaxf(x1, -8.f), 8.f);
    x2 = fminf(fmaxf(x2, -8.f), 8.f);
    float y1 = (x1 * cs - x2 * sn) * qscale;
    float y2 = (x2 * cs + x1 * sn) * qscale;
    size_t qb = ((size_t)(b * H_ + h) * S_ + s) * D_;
    Qs[qb + i]      = __float2bfloat16(y1);
    Qs[qb + 64 + i] = __float2bfloat16(y2);
  }
  {
    int kh = hq;
    float x1 = __bfloat162float(R[2048 + kh * 128 + i]);
    float x2 = __bfloat162float(R[2048 + kh * 128 + 64 + i]);
    x1 = fminf(fmaxf(x1, -8.f), 8.f);
    x2 = fminf(fmaxf(x2, -8.f), 8.f);
    float y1 = x1 * cs - x2 * sn;
    float y2 = x2 * cs + x1 * sn;
    size_t kb = ((size_t)(b * HKV_ + kh) * S_ + s) * D_;
    Ks[kb + i]      = __float2bfloat16(y1);
    Ks[kb + 64 + i] = __float2bfloat16(y2);
  }
}

// ---------------------------------------------------------------- flash attention, QBLK=32/wave, LDS-staged
// Plds rows padded to 40 elems (80 B stride): P-write banks period-8, 2 lanes/bank (free).
__global__ __launch_bounds__(256) void attn_fwd(const bf16* __restrict__ Qs,
                                                const bf16* __restrict__ Ks,
                                                const bf16* __restrict__ Vt,
                                                const int* __restrict__ sstart,
                                                bf16* __restrict__ att) {  // [B][S][H*D]
  __shared__ bf16 Kl[2][32 * 128];
  __shared__ bf16 Vl[2][128 * 32];
  __shared__ bf16 Plds[4][2][16 * 40];   // padded rows

  const int tid = threadIdx.x;
  const int lane = tid & 63, w = tid >> 6;
  const int ln15 = lane & 15, g = lane >> 4;

  const int wg = ((blockIdx.x & 7) << 6) | (blockIdx.x >> 3);
  const int qt  = wg & 63;
  const int kvh = (wg >> 6) & 3;
  const int b   = wg >> 8;
  const int h   = kvh * 4 + w;
  const int q0  = qt * 32;
  const int qa  = q0 + ln15;
  const int qb  = q0 + 16 + ln15;

  const bf16* Qbase = Qs + (size_t)(b * H_ + h) * S_ * D_;
  bf16x8 qfa[4], qfb[4];
#pragma unroll
  for (int c = 0; c < 4; c++) {
    qfa[c] = *reinterpret_cast<const bf16x8*>(Qbase + (size_t)qa * D_ + c * 32 + g * 8);
    qfb[c] = *reinterpret_cast<const bf16x8*>(Qbase + (size_t)qb * D_ + c * 32 + g * 8);
  }

  const int sQa = sstart[b * S_ + qa];
  const int sQb = sstart[b * S_ + qb];
  const int kstart = __builtin_amdgcn_readfirstlane(__shfl(sQa, 0));
  const int kend = q0 + 31;

  const bf16* Kb = Ks + (size_t)(b * HKV_ + kvh) * S_ * D_;
  const bf16* Vb = Vt + (size_t)(b * HKV_ + kvh) * D_ * S_;

  auto stage = [&](int buf, int kb) {
#pragma unroll
    for (int p = 0; p < 2; p++) {
      int slot = p * 256 + tid;
      int row = slot >> 4;
      int cs = (slot & 15) ^ (row & 15);
      int gr = min(kb + row, S_ - 1);
      GLOAD_LDS(Kb + (size_t)gr * D_ + cs * 8, &Kl[buf][(p * 256 + w * 64) * 8]);
    }
#pragma unroll
    for (int p = 0; p < 2; p++) {
      int slot = p * 256 + tid;
      int d = slot >> 2, c = slot & 3;
      int cs = c ^ (d & 3);
      int gcol = min(kb + cs * 8, S_ - 8);
      GLOAD_LDS(Vb + (size_t)d * S_ + gcol, &Vl[buf][(p * 256 + w * 64) * 8]);
    }
  };

  float ma = -1e30f, la = 0.f, mb = -1e30f, lb = 0.f;
  f32x4 oa[8] = {}, ob[8] = {};

  auto softmax = [&](const f32x4& s0, const f32x4& s1, int qi, int sQ, int kb,
                     float& m, float& lsum, f32x4 (&o)[8], bf16* pdst) {
    float sc[8];
    float tmax = -1e30f;
#pragma unroll
    for (int r = 0; r < 4; r++) {
      int k0i = kb + g * 4 + r;
      int k1i = k0i + 16;
      float x0 = (k0i >= sQ && k0i <= qi) ? s0[r] : -1e30f;
      float x1 = (k1i >= sQ && k1i <= qi) ? s1[r] : -1e30f;
      sc[r] = x0;
      sc[4 + r] = x1;
      tmax = fmaxf(tmax, fmaxf(x0, x1));
    }
    tmax = fmaxf(tmax, __shfl_xor(tmax, 16));
    tmax = fmaxf(tmax, __shfl_xor(tmax, 32));
    float mn  = fmaxf(m, tmax);
    float fac = __expf(m - mn);
    float ps = 0.f;
    alignas(16) bf16 pb[8];
#pragma unroll
    for (int i2 = 0; i2 < 8; i2++) {
      float p = (sc[i2] < -1e29f) ? 0.f : __expf(sc[i2] - mn);
      ps += p;
      pb[i2] = __float2bfloat16(p);
    }
    ps += __shfl_xor(ps, 16);
    ps += __shfl_xor(ps, 32);
    lsum = lsum * fac + ps;
    m = mn;
#pragma unroll
    for (int t2 = 0; t2 < 8; t2++) o[t2] *= fac;
    *reinterpret_cast<short4*>(pdst + ln15 * 40 + g * 4)      = *reinterpret_cast<const short4*>(&pb[0]);
    *reinterpret_cast<short4*>(pdst + ln15 * 40 + 16 + g * 4) = *reinterpret_cast<const short4*>(&pb[4]);
  };

  stage(0, kstart);
  int buf = 0;
  for (int kb = kstart; kb <= kend; kb += 32) {
    __syncthreads();
    if (kb + 32 <= kend) stage(buf ^ 1, kb + 32);

    bf16x8 kf0[4], kf1[4];
#pragma unroll
    for (int c = 0; c < 4; c++) {
      kf0[c] = *reinterpret_cast<const bf16x8*>(&Kl[buf][ln15 * 128 + (((c * 4 + g) ^ ln15) << 3)]);
      kf1[c] = *reinterpret_cast<const bf16x8*>(&Kl[buf][(16 + ln15) * 128 + (((c * 4 + g) ^ ln15) << 3)]);
    }
    f32x4 sa0 = {0.f, 0.f, 0.f, 0.f}, sa1 = sa0, sb0 = sa0, sb1 = sa0;
#pragma unroll
    for (int c = 0; c < 4; c++) {
      sa0 = MFMA_BF16(kf0[c], qfa[c], sa0);
      sa1 = MFMA_BF16(kf1[c], qfa[c], sa1);
      sb0 = MFMA_BF16(kf0[c], qfb[c], sb0);
      sb1 = MFMA_BF16(kf1[c], qfb[c], sb1);
    }

    softmax(sa0, sa1, qa, sQa, kb, ma, la, oa, &Plds[w][0][0]);
    softmax(sb0, sb1, qb, sQb, kb, mb, lb, ob, &Plds[w][1][0]);
    __builtin_amdgcn_wave_barrier();
    bf16x8 pfa = *reinterpret_cast<const bf16x8*>(&Plds[w][0][ln15 * 40 + g * 8]);
    bf16x8 pfb = *reinterpret_cast<const bf16x8*>(&Plds[w][1][ln15 * 40 + g * 8]);

#pragma unroll
    for (int t2 = 0; t2 < 8; t2++) {
      int d = t2 * 16 + ln15;
      bf16x8 vf = *reinterpret_cast<const bf16x8*>(&Vl[buf][d * 32 + ((g ^ (ln15 & 3)) << 3)]);
      oa[t2] = MFMA_BF16(vf, pfa, oa[t2]);
      ob[t2] = MFMA_BF16(vf, pfb, ob[t2]);
    }
    __builtin_amdgcn_wave_barrier();
    buf ^= 1;
  }

  float inva = 1.f / la;
  float invb = 1.f / lb;
#pragma unroll
  for (int t2 = 0; t2 < 8; t2++)
#pragma unroll
    for (int r = 0; r < 4; r++) {
      int d = t2 * 16 + g * 4 + r;
      att[((size_t)(b * S_ + qa)) * (H_ * D_) + h * D_ + d] = __float2bfloat16(oa[t2][r] * inva);
      att[((size_t)(b * S_ + qb)) * (H_ * D_) + h * D_ + d] = __float2bfloat16(ob[t2][r] * invb);
    }
}

// ---------------------------------------------------------------- launcher
extern "C" void kernel_launch(void* const* d_in, const int* in_sizes, int n_in,
                              void* d_out, int out_size, void* d_ws, size_t ws_size,
                              hipStream_t stream) {
  const float* hidden = (const float*)d_in[0];
  const int* wpos = (const int*)d_in[1];
  const int* seq = (const int*)d_in[3];
  const float* Wq = (const float*)d_in[4];
  const float* Wk = (const float*)d_in[5];
  const float* Wv = (const float*)d_in[6];
  const float* Wo = (const float*)d_in[7];

  char* ws = (char*)d_ws;
  bf16* Xb   = (bf16*)(ws);
  bf16* Wqkv = (bf16*)(ws + 16777216);
  bf16* Wob  = (bf16*)(ws + 29360128);
  bf16* QKVb = (bf16*)(ws + 37748736);
  bf16* Ksb  = (bf16*)(ws + 62914560);
  bf16* Vtb  = (bf16*)(ws + 67108864);
  int*  sst  = (int*)(ws + 71303168);
  bf16* Qsb  = Xb;
  bf16* attb = QKVb;

  cvt_all<<<dim3(2080), dim3(256), 0, stream>>>(hidden, Wq, Wk, Wv, Wo, seq, Xb, Wqkv, Wob, sst);

  // QKV projection: [4096,2048] x [3072,2048]^T -> bf16 [4096,3072]; grid 16x16=256
  gemm8p<256, 192, 1><<<dim3(256), dim3(512), 0, stream>>>(Xb, Wqkv, (void*)QKVb, 4096, 3072, 2048);

  qkv_post<<<dim3(4352), dim3(256), 0, stream>>>(QKVb, wpos, Qsb, Ksb, Vtb);

  attn_fwd<<<dim3(512), dim3(256), 0, stream>>>(Qsb, Ksb, Vtb, sst, attb);

  // O projection: [4096,2048] x [2048,2048]^T -> fp32 d_out; grid 16x16=256
  gemm8p<256, 128, 0><<<dim3(256), dim3(512), 0, stream>>>(attb, Wob, d_out, 4096, 2048, 2048);
}